// Round 2
// baseline (265.116 us; speedup 1.0000x reference)
//
#include <hip/hip_runtime.h>

#define EMB 2048
#define UDIM 256
#define KTOT 2304
#define NE 64
#define TOPK 8
#define TPB 16               // tokens per block: one 16-token MFMA tile
#define LP 65                // reduce-slab row stride (bank-conflict pad)
#define SSH 6144             // shorts per k-step in wb: 3 planes * 4 nt * 64 lanes * 8

typedef __attribute__((ext_vector_type(8))) short short8;
typedef __attribute__((ext_vector_type(4))) float f32x4;
typedef __attribute__((ext_vector_type(4))) unsigned int u32x4;

__device__ __forceinline__ unsigned short bf16h(float x) {
  unsigned uu = __builtin_bit_cast(unsigned, x);
  return (unsigned short)((uu + 0x7FFFu + ((uu >> 16) & 1u)) >> 16);
}
__device__ __forceinline__ float bf2f(unsigned short s) {
  return __builtin_bit_cast(float, ((unsigned)s) << 16);
}

// packed RNE f32x2 -> bf16x2 (no builtin on gfx950; guide T12 recipe)
__device__ __forceinline__ unsigned cvtpk(float a, float b) {
  unsigned r;
  asm("v_cvt_pk_bf16_f32 %0, %1, %2" : "=v"(r) : "v"(a), "v"(b));
  return r;
}

// ---- prep: W fp32 [2304][64] -> triple-split bf16 in MFMA-FRAGMENT order ----
// wb[kstep][plane][nt][lane][j]:  lane = (kk>>3)*16 + (n&15), j = kk&7
// => each wave B-load is base + lane*16B: ONE coalesced dwordx4, 4 lines.
__global__ __launch_bounds__(256)
void prep_w(const float* __restrict__ W, unsigned short* __restrict__ wb) {
  const int flat = blockIdx.x * 256 + threadIdx.x;  // 0..147455
  const int k = flat >> 6;
  const int n = flat & 63;
  const float w = W[flat];  // coalesced read
  const unsigned short h0 = bf16h(w);
  const float r1 = w - bf2f(h0);   // exact in fp32
  const unsigned short h1 = bf16h(r1);
  const float r2 = r1 - bf2f(h1);  // exact in fp32
  const unsigned short h2 = bf16h(r2);

  const int s = k >> 5;
  const int kk = k & 31;
  const int lane = (kk >> 3) * 16 + (n & 15);
  const int j = kk & 7;
  const int nt = n >> 4;
  const size_t base = (size_t)s * SSH + ((size_t)nt * 64 + lane) * 8 + j;
  wb[base] = h0;                    // plane 0
  wb[base + 2048] = h1;             // plane 1 (4*64*8 shorts per plane-step)
  wb[base + 4096] = h2;             // plane 2
}

// ---- main: triple-split bf16 MFMA GEMM + softmax + top-8 ----
// 8-way K-split (9 k-steps each), 32 waves/CU target.
__global__ __launch_bounds__(512, 8)
void gate_mfma(const float* __restrict__ h, const float* __restrict__ u,
               const unsigned short* __restrict__ wb,
               const float* __restrict__ b, float* __restrict__ out) {
  __shared__ float slab[4][TPB * LP];  // 4 reduce buffers, 16.6 KB

  const int tid = threadIdx.x;
  const int lane = tid & 63;
  const int kq = __builtin_amdgcn_readfirstlane(tid >> 6);  // K slice 0..7
  const int mm = lane & 15;        // A: token-in-tile | B: expert-in-tile
  const int q8 = (lane >> 4) * 8;  // k-subgroup offset within frag
  const int tok0 = blockIdx.x * TPB;
  const int token = tok0 + mm;

  const float* hrow = h + (size_t)token * EMB + q8;
  const float* urow = u + (size_t)token * UDIM + q8;
  const unsigned short* wlane = wb + (size_t)lane * 8;  // per-lane frag base

  f32x4 acc[4];
#pragma unroll
  for (int nt = 0; nt < 4; ++nt) acc[nt] = 0.f;

  // one GEMM segment, steps of 32 k.
  // Issue order per step: B loads (12, L2-hot) FIRST, then next-step A
  // prefetch -> MFMA's wait on B is vmcnt(2), A's wait is vmcnt(14):
  // neither drains the other's prefetch.
  auto run = [&](const float* __restrict__ xp, int kw0, int nsteps) {
    f32x4 c0 = *(const f32x4*)(xp);
    f32x4 c1 = *(const f32x4*)(xp + 4);
    const int as0 = kw0 >> 5;  // absolute k-step index
    for (int s = 0; s < nsteps; ++s) {
      // B frag loads: 12 coalesced dwordx4
      const unsigned short* ws = wlane + (size_t)(as0 + s) * SSH;
      short8 Bv[3][4];
#pragma unroll
      for (int p = 0; p < 3; ++p)
#pragma unroll
        for (int nt = 0; nt < 4; ++nt)
          Bv[p][nt] = *(const short8*)(ws + (p * 4 + nt) * 512);

      // A prefetch 1 ahead (TLP at 8 waves/SIMD covers the rest)
      f32x4 n0 = 0.f, n1 = 0.f;
      if (s + 1 < nsteps) {
        n0 = *(const f32x4*)(xp + (s + 1) * 32);
        n1 = *(const f32x4*)(xp + (s + 1) * 32 + 4);
      }

      // triple-split current A via packed converts: x = A0+A1+A2.
      // Split remainders are exact in fp32 regardless of rounding mode.
      float xs[8] = {c0[0], c0[1], c0[2], c0[3], c1[0], c1[1], c1[2], c1[3]};
      u32x4 W0, W1, W2;
#pragma unroll
      for (int k2 = 0; k2 < 4; ++k2) {
        const float a = xs[2 * k2], bb = xs[2 * k2 + 1];
        const unsigned p0 = cvtpk(a, bb);
        const float a1 = a - __builtin_bit_cast(float, p0 << 16);
        const float b1 = bb - __builtin_bit_cast(float, p0 & 0xFFFF0000u);
        const unsigned p1 = cvtpk(a1, b1);
        const float a2 = a1 - __builtin_bit_cast(float, p1 << 16);
        const float b2 = b1 - __builtin_bit_cast(float, p1 & 0xFFFF0000u);
        const unsigned p2 = cvtpk(a2, b2);
        W0[k2] = p0; W1[k2] = p1; W2[k2] = p2;
      }
      const short8 A0 = __builtin_bit_cast(short8, W0);
      const short8 A1 = __builtin_bit_cast(short8, W1);
      const short8 A2 = __builtin_bit_cast(short8, W2);

      // 4 n-tiles x 6 split terms
#pragma unroll
      for (int nt = 0; nt < 4; ++nt) {
        acc[nt] = __builtin_amdgcn_mfma_f32_16x16x32_bf16(A0, Bv[0][nt], acc[nt], 0, 0, 0);
        acc[nt] = __builtin_amdgcn_mfma_f32_16x16x32_bf16(A0, Bv[1][nt], acc[nt], 0, 0, 0);
        acc[nt] = __builtin_amdgcn_mfma_f32_16x16x32_bf16(A1, Bv[0][nt], acc[nt], 0, 0, 0);
        acc[nt] = __builtin_amdgcn_mfma_f32_16x16x32_bf16(A1, Bv[1][nt], acc[nt], 0, 0, 0);
        acc[nt] = __builtin_amdgcn_mfma_f32_16x16x32_bf16(A0, Bv[2][nt], acc[nt], 0, 0, 0);
        acc[nt] = __builtin_amdgcn_mfma_f32_16x16x32_bf16(A2, Bv[0][nt], acc[nt], 0, 0, 0);
      }
      c0 = n0; c1 = n1;
    }
  };

  if (kq < 7) {
    run(hrow + kq * 288, kq * 288, 9);    // pure h: 288 k each
  } else {
    run(hrow + 2016, 2016, 1);            // h tail: [2016,2048)
    run(urow, 2048, 8);                   // u: [2048,2304)
  }

  // ---- 2-phase K reduce into 4 slab buffers ----
  // D layout: row(token) = (lane>>4)*4 + reg, col(expert%16) = mm
  const int row = (lane >> 4) * 4;
  const int bsel = kq & 3;
  if (kq < 4) {
#pragma unroll
    for (int nt = 0; nt < 4; ++nt)
#pragma unroll
      for (int r = 0; r < 4; ++r)
        slab[bsel][(row + r) * LP + nt * 16 + mm] = acc[nt][r];
  }
  __syncthreads();
  if (kq >= 4) {
#pragma unroll
    for (int nt = 0; nt < 4; ++nt)
#pragma unroll
      for (int r = 0; r < 4; ++r)
        slab[bsel][(row + r) * LP + nt * 16 + mm] += acc[nt][r];
  }
  __syncthreads();

  // ---- epilogue: wave kq handles tokens [2*kq, 2*kq+2); lane = expert ----
  const float bias = b[lane];
#pragma unroll
  for (int tt = 0; tt < 2; ++tt) {
    const int t = kq * 2 + tt;
    float g = slab[0][t * LP + lane] + slab[1][t * LP + lane] +
              slab[2][t * LP + lane] + slab[3][t * LP + lane] + bias;

    float m = g;
#pragma unroll
    for (int off = 32; off > 0; off >>= 1)
      m = fmaxf(m, __shfl_xor(m, off));
    float pexp = __expf(g - m);
    float s = pexp;
#pragma unroll
    for (int off = 32; off > 0; off >>= 1)
      s += __shfl_xor(s, off);
    const float pn = pexp / s;

    float vv = pn;
    float topsum = 0.f;
    int sel = 0;
    for (int r = 0; r < TOPK; ++r) {
      float mv = vv;
      int mi = lane;
#pragma unroll
      for (int off = 32; off > 0; off >>= 1) {
        const float ov = __shfl_xor(mv, off);
        const int oi = __shfl_xor(mi, off);
        if (ov > mv || (ov == mv && oi < mi)) { mv = ov; mi = oi; }
      }
      topsum += mv;
      if (lane == mi) { sel = 1; vv = -1.f; }
    }

    out[(size_t)(tok0 + t) * NE + lane] =
        sel ? pn / (topsum + 1e-9f) : 0.f;
  }
}

extern "C" void kernel_launch(void* const* d_in, const int* in_sizes, int n_in,
                              void* d_out, int out_size, void* d_ws, size_t ws_size,
                              hipStream_t stream) {
  const float* h = (const float*)d_in[0];
  const float* u = (const float*)d_in[1];
  const float* W = (const float*)d_in[2];
  const float* b = (const float*)d_in[3];
  float* out = (float*)d_out;

  unsigned short* wb = (unsigned short*)d_ws;  // 72*6144 shorts = 884736 B

  const int n_tokens = in_sizes[0] / EMB;  // 16384

  hipLaunchKernelGGL(prep_w, dim3(KTOT * NE / 256), dim3(256), 0, stream, W, wb);
  hipLaunchKernelGGL(gate_mfma, dim3(n_tokens / TPB), dim3(512), 0, stream,
                     h, u, wb, b, out);
}